// Round 1
// baseline (237.423 us; speedup 1.0000x reference)
//
#include <hip/hip_runtime.h>

// LocallyConnected3DFlipout: out[b,p,f] = sum_k patch[b,p,k]*loc[p,k,f]
//   + sign_out[b,p,f]*sum_k (x*sign_in)patch[b,p,k]*(softplus(rho)*eps)[p,k,f]
//   + bias[f]
// patch k-index = c*27 + (kd*9 + kh*3 + kw)  (conv_general_dilated_patches:
// input-channel slowest, filter spatial row-major fastest).

constexpr int Bn   = 32;
constexpr int Dn   = 30;
constexpr int Cn   = 4;
constexpr int ODn  = 28;
constexpr int Pn   = ODn * ODn * ODn;   // 21952
constexpr int Tt   = 27;                // spatial taps
constexpr int Kn   = Tt * Cn;           // 108
constexpr int Fn   = 4;
constexpr int PPB  = 8;                 // output positions per block (21952 % 8 == 0)
constexpr int THREADS = 256;            // 32 batches x 8 positions

__global__ __launch_bounds__(THREADS) void lc3d_flipout_kernel(
    const float* __restrict__ x,        // [B,30,30,30,4]
    const float* __restrict__ loc,      // [P,108,4]
    const float* __restrict__ rho,      // [P,108,4]
    const float* __restrict__ bias,     // [4]
    const float* __restrict__ eps,      // [P,108,4]
    const float* __restrict__ sgn_in,   // [B,30,30,30,4]
    const float* __restrict__ sgn_out,  // [B,P,4]
    float* __restrict__ out)            // [B,P,4]
{
    // LDS weight slabs, layout [p_loc][t][c] -> float4 over f (so the 4 f's a
    // thread needs are one ds_read_b128; per-instruction only 2 distinct
    // addresses per wave -> broadcast, conflict-free).
    __shared__ float4 wm[PPB * Tt * Cn];   // mean weights (= loc)
    __shared__ float4 wn[PPB * Tt * Cn];   // noise weights (= softplus(rho)*eps)

    const int tid    = threadIdx.x;
    const int p_base = blockIdx.x * PPB;

    // ---- Stage weights: PPB*K*F = 3456 floats = 864 float4 per array ----
    // Global float4 index g covers (p_loc, c, t) with t fastest; f packed in lanes.
    const float4* loc4 = (const float4*)loc + (size_t)p_base * Kn;
    const float4* rho4 = (const float4*)rho + (size_t)p_base * Kn;
    const float4* eps4 = (const float4*)eps + (size_t)p_base * Kn;

    for (int g = tid; g < PPB * Kn; g += THREADS) {
        const int p_loc = g / Kn;
        const int rem   = g - p_loc * Kn;
        const int c     = rem / Tt;
        const int t     = rem - c * Tt;
        const float4 L = loc4[g];
        const float4 R = rho4[g];
        const float4 E = eps4[g];
        float4 W;
        W.x = (R.x > 15.f ? R.x : __logf(1.f + __expf(R.x))) * E.x;
        W.y = (R.y > 15.f ? R.y : __logf(1.f + __expf(R.y))) * E.y;
        W.z = (R.z > 15.f ? R.z : __logf(1.f + __expf(R.z))) * E.z;
        W.w = (R.w > 15.f ? R.w : __logf(1.f + __expf(R.w))) * E.w;
        const int l = p_loc * Kn + t * Cn + c;   // permute [c][t] -> [t][c]
        wm[l] = L;
        wn[l] = W;
    }
    __syncthreads();

    // ---- Each thread: one (b, p), all 4 filters ----
    const int b     = tid & 31;
    const int p_loc = tid >> 5;
    const int p     = p_base + p_loc;
    const int od    = p / (ODn * ODn);
    const int prem  = p - od * (ODn * ODn);
    const int oh    = prem / ODn;
    const int ow    = prem - oh * ODn;

    // voxel index (float4 units: each voxel is 4 contiguous channels = 16 B)
    const size_t vox = (((size_t)b * Dn + od) * Dn + oh) * Dn + ow;
    const float4* xb = (const float4*)x      + vox;
    const float4* sb = (const float4*)sgn_in + vox;
    const float4* wmp = wm + p_loc * Kn;
    const float4* wnp = wn + p_loc * Kn;

    float am0 = 0.f, am1 = 0.f, am2 = 0.f, am3 = 0.f;
    float an0 = 0.f, an1 = 0.f, an2 = 0.f, an3 = 0.f;

    #pragma unroll
    for (int kd = 0; kd < 3; ++kd) {
        #pragma unroll
        for (int kh = 0; kh < 3; ++kh) {
            const float4* xr = xb + (kd * Dn + kh) * Dn;
            const float4* sr = sb + (kd * Dn + kh) * Dn;
            #pragma unroll
            for (int kw = 0; kw < 3; ++kw) {
                const int t = (kd * 3 + kh) * 3 + kw;
                const float4 xv = xr[kw];
                const float4 sv = sr[kw];
                const float4 m0 = wmp[t * Cn + 0];
                const float4 m1 = wmp[t * Cn + 1];
                const float4 m2 = wmp[t * Cn + 2];
                const float4 m3 = wmp[t * Cn + 3];
                const float4 n0 = wnp[t * Cn + 0];
                const float4 n1 = wnp[t * Cn + 1];
                const float4 n2 = wnp[t * Cn + 2];
                const float4 n3 = wnp[t * Cn + 3];

                am0 = fmaf(xv.x, m0.x, am0); am0 = fmaf(xv.y, m1.x, am0);
                am0 = fmaf(xv.z, m2.x, am0); am0 = fmaf(xv.w, m3.x, am0);
                am1 = fmaf(xv.x, m0.y, am1); am1 = fmaf(xv.y, m1.y, am1);
                am1 = fmaf(xv.z, m2.y, am1); am1 = fmaf(xv.w, m3.y, am1);
                am2 = fmaf(xv.x, m0.z, am2); am2 = fmaf(xv.y, m1.z, am2);
                am2 = fmaf(xv.z, m2.z, am2); am2 = fmaf(xv.w, m3.z, am2);
                am3 = fmaf(xv.x, m0.w, am3); am3 = fmaf(xv.y, m1.w, am3);
                am3 = fmaf(xv.z, m2.w, am3); am3 = fmaf(xv.w, m3.w, am3);

                const float xs0 = xv.x * sv.x;
                const float xs1 = xv.y * sv.y;
                const float xs2 = xv.z * sv.z;
                const float xs3 = xv.w * sv.w;

                an0 = fmaf(xs0, n0.x, an0); an0 = fmaf(xs1, n1.x, an0);
                an0 = fmaf(xs2, n2.x, an0); an0 = fmaf(xs3, n3.x, an0);
                an1 = fmaf(xs0, n0.y, an1); an1 = fmaf(xs1, n1.y, an1);
                an1 = fmaf(xs2, n2.y, an1); an1 = fmaf(xs3, n3.y, an1);
                an2 = fmaf(xs0, n0.z, an2); an2 = fmaf(xs1, n1.z, an2);
                an2 = fmaf(xs2, n2.z, an2); an2 = fmaf(xs3, n3.z, an2);
                an3 = fmaf(xs0, n0.w, an3); an3 = fmaf(xs1, n1.w, an3);
                an3 = fmaf(xs2, n2.w, an3); an3 = fmaf(xs3, n3.w, an3);
            }
        }
    }

    // ---- Epilogue: flipout combine + bias, coalesced float4 store ----
    const size_t ob = (size_t)b * Pn + p;      // float4 units
    const float4 so = ((const float4*)sgn_out)[ob];
    const float4 bi = *(const float4*)bias;
    float4 o;
    o.x = fmaf(so.x, an0, am0) + bi.x;
    o.y = fmaf(so.y, an1, am1) + bi.y;
    o.z = fmaf(so.z, an2, am2) + bi.z;
    o.w = fmaf(so.w, an3, am3) + bi.w;
    ((float4*)out)[ob] = o;
}

extern "C" void kernel_launch(void* const* d_in, const int* in_sizes, int n_in,
                              void* d_out, int out_size, void* d_ws, size_t ws_size,
                              hipStream_t stream) {
    const float* x    = (const float*)d_in[0];
    const float* loc  = (const float*)d_in[1];
    const float* rho  = (const float*)d_in[2];
    const float* bias = (const float*)d_in[3];
    const float* eps  = (const float*)d_in[4];
    const float* si   = (const float*)d_in[5];
    const float* so   = (const float*)d_in[6];
    float* out = (float*)d_out;

    lc3d_flipout_kernel<<<dim3(Pn / PPB), dim3(THREADS), 0, stream>>>(
        x, loc, rho, bias, eps, si, so, out);
}